// Round 9
// baseline (113.655 us; speedup 1.0000x reference)
//
#include <hip/hip_runtime.h>
#include <math.h>

// Grid 2048 x 256. Each block = 4 independent waves; each wave processes 2
// consecutive 32x32 images (16 px/thread) with the two images' pipelines
// interleaved (separate LDS slices per image). No __syncthreads: waves use
// disjoint LDS slices; LDS pipe is in-order within a wave;
// __builtin_amdgcn_wave_barrier() fences compiler reordering.
//
// R9 change: PLAIN stores instead of __builtin_nontemporal_store. nt stores
// bypass L2 -> store completion is an HBM ack (~900cy) and every wave
// serializes on the HBM write queue at the pre-endpgm vmcnt(0) drain. Plain
// stores complete at L2 (~200cy) and drain to HBM asynchronously after
// wave retirement (a block's 32KB output fits its XCD L2 easily).
//
// FAST PATH (all 8 neighbor weights equal — true for the Laplacian):
// conv = k0*sum9 + (k4-k0)*x, sum9 separable: horizontal rowsums in
// registers (neighbors via zero-fill wave DPP shifts), staged to LDS,
// vertical = 2 b128 reads + own rowsum.
// Generic fallback: raw 9-fma conv via LDS tile, sequential.
// LDS slice: 34 rows x stride 36 + pad = 1228 floats; data at col+4
// (16B-aligned b128). Rows 0/33 zeroed (vertical pad). 2 slices/wave.

#define S 36
#define SLICE 1228

typedef float floatx4 __attribute__((ext_vector_type(4)));

template <int CTRL>
__device__ __forceinline__ float dppmov(float x) {
    // old = src => bound lanes keep x (identity for min/max)
    return __int_as_float(__builtin_amdgcn_update_dpp(
        __float_as_int(x), __float_as_int(x), CTRL, 0xf, 0xf, false));
}

template <int CTRL>
__device__ __forceinline__ float dppsh0(float x) {
    // zero-fill wave shift: old = 0, bound_ctrl = true
    return __int_as_float(__builtin_amdgcn_update_dpp(
        0, __float_as_int(x), CTRL, 0xf, 0xf, true));
}

// 4-value interleaved wave64 min/max reduction (2 images).
__device__ __forceinline__ void wave64_minmax2(float& mnA, float& mxA,
                                               float& mnB, float& mxB) {
#define STEP(C)                                                   \
    mnA = fminf(mnA, dppmov<C>(mnA)); mxA = fmaxf(mxA, dppmov<C>(mxA)); \
    mnB = fminf(mnB, dppmov<C>(mnB)); mxB = fmaxf(mxB, dppmov<C>(mxB));
    STEP(0x111) STEP(0x112) STEP(0x114) STEP(0x118) STEP(0x142) STEP(0x143)
#undef STEP
    // lane 63 holds the wave-wide values
}

__device__ __forceinline__ void wave64_minmax(float& mn, float& mx) {
    mn = fminf(mn, dppmov<0x111>(mn)); mx = fmaxf(mx, dppmov<0x111>(mx));
    mn = fminf(mn, dppmov<0x112>(mn)); mx = fmaxf(mx, dppmov<0x112>(mx));
    mn = fminf(mn, dppmov<0x114>(mn)); mx = fmaxf(mx, dppmov<0x114>(mx));
    mn = fminf(mn, dppmov<0x118>(mn)); mx = fmaxf(mx, dppmov<0x118>(mx));
    mn = fminf(mn, dppmov<0x142>(mn)); mx = fmaxf(mx, dppmov<0x142>(mx));
    mn = fminf(mn, dppmov<0x143>(mn)); mx = fmaxf(mx, dppmov<0x143>(mx));
}

__device__ __forceinline__ float rd63(float v) {
    return __int_as_float(__builtin_amdgcn_readlane(__float_as_int(v), 63));
}

__device__ __forceinline__ void local_minmax16(const float v[4][4],
                                               float& mn, float& mx) {
    mn = v[0][0]; mx = v[0][0];
#pragma unroll
    for (int i = 0; i < 4; ++i)
#pragma unroll
        for (int j = 0; j < 4; ++j) {
            mn = fminf(mn, v[i][j]);
            mx = fmaxf(mx, v[i][j]);
        }
}

// Generic fallback (sequential, slice sm; halo cols 0,3 must be zeroed).
__device__ __forceinline__ void process_image_gen(
    float* __restrict__ sm, const float4* __restrict__ x4, const float* k,
    float* __restrict__ dst, int lane)
{
    const int rbase = lane >> 3;
    const int col0  = (lane & 7) << 2;

    __builtin_amdgcn_wave_barrier();
#pragma unroll
    for (int i = 0; i < 4; ++i)
        *(float4*)&sm[(i * 8 + rbase + 1) * S + (col0 + 4)] = x4[i];
    __builtin_amdgcn_wave_barrier();

    float conv[4][4];
#pragma unroll
    for (int i = 0; i < 4; ++i) {
        const int row = i * 8 + rbase;
        const float* pt = &sm[ row      * S + col0];
        const float* pm = &sm[(row + 1) * S + col0];
        const float* pb = &sm[(row + 2) * S + col0];
        const float  tl = pt[3], tr = pt[8];
        const float4 tm = *(const float4*)(pt + 4);
        const float  ml = pm[3], mr = pm[8];
        const float  bl = pb[3], br = pb[8];
        const float4 bm = *(const float4*)(pb + 4);
        const float4 m  = x4[i];
        conv[i][0] = k[0]*tl   + k[1]*tm.x + k[2]*tm.y
                   + k[3]*ml   + k[4]*m.x  + k[5]*m.y
                   + k[6]*bl   + k[7]*bm.x + k[8]*bm.y;
        conv[i][1] = k[0]*tm.x + k[1]*tm.y + k[2]*tm.z
                   + k[3]*m.x  + k[4]*m.y  + k[5]*m.z
                   + k[6]*bm.x + k[7]*bm.y + k[8]*bm.z;
        conv[i][2] = k[0]*tm.y + k[1]*tm.z + k[2]*tm.w
                   + k[3]*m.y  + k[4]*m.z  + k[5]*m.w
                   + k[6]*bm.y + k[7]*bm.z + k[8]*bm.w;
        conv[i][3] = k[0]*tm.z + k[1]*tm.w + k[2]*tr
                   + k[3]*m.z  + k[4]*m.w  + k[5]*mr
                   + k[6]*bm.z + k[7]*bm.w + k[8]*br;
    }
    __builtin_amdgcn_wave_barrier();

    float mn, mx;
    local_minmax16(conv, mn, mx);
    wave64_minmax(mn, mx);
    const float cmin = rd63(mn), cmax = rd63(mx);
    const float inv1 = 255.0f / fmaxf(cmax - cmin, 1e-6f);
    float sh[4][4];
#pragma unroll
    for (int i = 0; i < 4; ++i) {
        sh[i][0] = x4[i].x + (conv[i][0] - cmin) * inv1;
        sh[i][1] = x4[i].y + (conv[i][1] - cmin) * inv1;
        sh[i][2] = x4[i].z + (conv[i][2] - cmin) * inv1;
        sh[i][3] = x4[i].w + (conv[i][3] - cmin) * inv1;
    }
    local_minmax16(sh, mn, mx);
    wave64_minmax(mn, mx);
    const float smin = rd63(mn), smax = rd63(mx);
    const float inv2 = 255.0f / fminf(fmaxf(smax - smin, 1e-6f), 255.0f);
    const float c2 = -smin * inv2;
#pragma unroll
    for (int i = 0; i < 4; ++i) {
        float4 o;
        o.x = floorf(fminf(fmaxf(sh[i][0] * inv2 + c2, 0.0f), 255.0f));
        o.y = floorf(fminf(fmaxf(sh[i][1] * inv2 + c2, 0.0f), 255.0f));
        o.z = floorf(fminf(fmaxf(sh[i][2] * inv2 + c2, 0.0f), 255.0f));
        o.w = floorf(fminf(fmaxf(sh[i][3] * inv2 + c2, 0.0f), 255.0f));
        *(float4*)(dst + i * 256 + lane * 4) = o;
    }
}

__global__ __launch_bounds__(256) void laplacian_fwd_kernel(
    const float* __restrict__ in,      // (16384, 1, 32, 32)
    const float* __restrict__ weight,  // (1, 9)
    const float* __restrict__ wfac,    // (1, 1)
    float* __restrict__ out)           // (1, 16384, 1, 32, 32)
{
    __shared__ float lds[8 * SLICE];   // 2 slices per wave

    const int t    = threadIdx.x;
    const int w    = t >> 6;
    const int lane = t & 63;
    float* smA = &lds[(2 * w)     * SLICE];
    float* smB = &lds[(2 * w + 1) * SLICE];

    const int W = blockIdx.x * 4 + w;            // 0..8191
    const size_t base0 = (size_t)(2 * W) * 1024;
    const size_t base1 = base0 + 1024;

    const int rbase = lane >> 3;        // 0..7
    const int col0  = (lane & 7) << 2;  // 0,4,...,28
    const bool ledge = (lane & 7) == 0;
    const bool redge = (lane & 7) == 7;

    // Issue both images' loads immediately (8 independent b128 loads).
    float4 xa[4], xb[4];
#pragma unroll
    for (int i = 0; i < 4; ++i)
        xa[i] = *(const float4*)(in + base0 + i * 256 + lane * 4);
#pragma unroll
    for (int i = 0; i < 4; ++i)
        xb[i] = *(const float4*)(in + base1 + i * 256 + lane * 4);

    // Fast-path border zeros: rows 0 and 33 of both slices (36 wide).
    if (lane < 36) {
        smA[lane] = 0.0f; smA[33 * S + lane] = 0.0f;
        smB[lane] = 0.0f; smB[33 * S + lane] = 0.0f;
    }

    // Kernel coefficients (uniform).
    const float wf = fminf(fmaxf(wfac[0], 1.001f), 254.999f);
    float k[9];
#pragma unroll
    for (int i = 0; i < 9; ++i)
        k[i] = fminf(fmaxf(weight[i], -0.999f), 0.999f) * wf;

    const bool fast = (k[0] == k[1]) && (k[0] == k[2]) && (k[0] == k[3]) &&
                      (k[0] == k[5]) && (k[0] == k[6]) && (k[0] == k[7]) &&
                      (k[0] == k[8]);

    if (fast) {
        const float k0 = k[0];
        const float dk = k[4] - k[0];

        // ---- rowsums A and B (registers + DPP wave shifts), stage to LDS ----
        float4 rsA[4], rsB[4];
        __builtin_amdgcn_wave_barrier();
#pragma unroll
        for (int i = 0; i < 4; ++i) {
            const float4 m = xa[i];
            float lv = dppsh0<0x138>(m.w);  // wave_shr:1
            float rv = dppsh0<0x130>(m.x);  // wave_shl:1
            lv = ledge ? 0.0f : lv;
            rv = redge ? 0.0f : rv;
            const float t1 = m.x + m.y, t2 = m.z + m.w;
            rsA[i].x = lv + t1; rsA[i].y = t1 + m.z;
            rsA[i].z = m.y + t2; rsA[i].w = t2 + rv;
            *(float4*)&smA[(i * 8 + rbase + 1) * S + (col0 + 4)] = rsA[i];
        }
#pragma unroll
        for (int i = 0; i < 4; ++i) {
            const float4 m = xb[i];
            float lv = dppsh0<0x138>(m.w);
            float rv = dppsh0<0x130>(m.x);
            lv = ledge ? 0.0f : lv;
            rv = redge ? 0.0f : rv;
            const float t1 = m.x + m.y, t2 = m.z + m.w;
            rsB[i].x = lv + t1; rsB[i].y = t1 + m.z;
            rsB[i].z = m.y + t2; rsB[i].w = t2 + rv;
            *(float4*)&smB[(i * 8 + rbase + 1) * S + (col0 + 4)] = rsB[i];
        }
        __builtin_amdgcn_wave_barrier();

        // ---- conv A and B ----
        float cvA[4][4], cvB[4][4];
#pragma unroll
        for (int i = 0; i < 4; ++i) {
            const int row = i * 8 + rbase;
            const float4 top = *(const float4*)&smA[ row      * S + col0 + 4];
            const float4 bot = *(const float4*)&smA[(row + 2) * S + col0 + 4];
            cvA[i][0] = (top.x + rsA[i].x + bot.x) * k0 + dk * xa[i].x;
            cvA[i][1] = (top.y + rsA[i].y + bot.y) * k0 + dk * xa[i].y;
            cvA[i][2] = (top.z + rsA[i].z + bot.z) * k0 + dk * xa[i].z;
            cvA[i][3] = (top.w + rsA[i].w + bot.w) * k0 + dk * xa[i].w;
        }
#pragma unroll
        for (int i = 0; i < 4; ++i) {
            const int row = i * 8 + rbase;
            const float4 top = *(const float4*)&smB[ row      * S + col0 + 4];
            const float4 bot = *(const float4*)&smB[(row + 2) * S + col0 + 4];
            cvB[i][0] = (top.x + rsB[i].x + bot.x) * k0 + dk * xb[i].x;
            cvB[i][1] = (top.y + rsB[i].y + bot.y) * k0 + dk * xb[i].y;
            cvB[i][2] = (top.z + rsB[i].z + bot.z) * k0 + dk * xb[i].z;
            cvB[i][3] = (top.w + rsB[i].w + bot.w) * k0 + dk * xb[i].w;
        }
        __builtin_amdgcn_wave_barrier();

        // ---- reduction 1 (A,B interleaved) ----
        float mnA, mxA, mnB, mxB;
        local_minmax16(cvA, mnA, mxA);
        local_minmax16(cvB, mnB, mxB);
        wave64_minmax2(mnA, mxA, mnB, mxB);
        const float cminA = rd63(mnA), cmaxA = rd63(mxA);
        const float cminB = rd63(mnB), cmaxB = rd63(mxB);
        const float inv1A = 255.0f / fmaxf(cmaxA - cminA, 1e-6f);
        const float inv1B = 255.0f / fmaxf(cmaxB - cminB, 1e-6f);

        // sharpened (in place over conv)
#pragma unroll
        for (int i = 0; i < 4; ++i) {
            cvA[i][0] = xa[i].x + (cvA[i][0] - cminA) * inv1A;
            cvA[i][1] = xa[i].y + (cvA[i][1] - cminA) * inv1A;
            cvA[i][2] = xa[i].z + (cvA[i][2] - cminA) * inv1A;
            cvA[i][3] = xa[i].w + (cvA[i][3] - cminA) * inv1A;
            cvB[i][0] = xb[i].x + (cvB[i][0] - cminB) * inv1B;
            cvB[i][1] = xb[i].y + (cvB[i][1] - cminB) * inv1B;
            cvB[i][2] = xb[i].z + (cvB[i][2] - cminB) * inv1B;
            cvB[i][3] = xb[i].w + (cvB[i][3] - cminB) * inv1B;
        }

        // ---- reduction 2 (A,B interleaved) ----
        local_minmax16(cvA, mnA, mxA);
        local_minmax16(cvB, mnB, mxB);
        wave64_minmax2(mnA, mxA, mnB, mxB);
        const float sminA = rd63(mnA), smaxA = rd63(mxA);
        const float sminB = rd63(mnB), smaxB = rd63(mxB);
        const float inv2A = 255.0f / fminf(fmaxf(smaxA - sminA, 1e-6f), 255.0f);
        const float inv2B = 255.0f / fminf(fmaxf(smaxB - sminB, 1e-6f), 255.0f);
        const float c2A = -sminA * inv2A;
        const float c2B = -sminB * inv2B;

        float* dstA = out + base0;
        float* dstB = out + base1;
#pragma unroll
        for (int i = 0; i < 4; ++i) {
            float4 oA, oB;
            oA.x = floorf(fminf(fmaxf(cvA[i][0] * inv2A + c2A, 0.0f), 255.0f));
            oA.y = floorf(fminf(fmaxf(cvA[i][1] * inv2A + c2A, 0.0f), 255.0f));
            oA.z = floorf(fminf(fmaxf(cvA[i][2] * inv2A + c2A, 0.0f), 255.0f));
            oA.w = floorf(fminf(fmaxf(cvA[i][3] * inv2A + c2A, 0.0f), 255.0f));
            *(float4*)(dstA + i * 256 + lane * 4) = oA;
            oB.x = floorf(fminf(fmaxf(cvB[i][0] * inv2B + c2B, 0.0f), 255.0f));
            oB.y = floorf(fminf(fmaxf(cvB[i][1] * inv2B + c2B, 0.0f), 255.0f));
            oB.z = floorf(fminf(fmaxf(cvB[i][2] * inv2B + c2B, 0.0f), 255.0f));
            oB.w = floorf(fminf(fmaxf(cvB[i][3] * inv2B + c2B, 0.0f), 255.0f));
            *(float4*)(dstB + i * 256 + lane * 4) = oB;
        }
    } else {
        // Generic path (correctness only): zero slice-A halos, run twice.
        if (lane < 36) { smA[lane] = 0.0f; smA[33 * S + lane] = 0.0f; }
        if (lane < 32) { smA[(lane + 1) * S] = 0.0f; smA[(lane + 1) * S + 3] = 0.0f; }
        if (lane == 0) smA[34 * S] = 0.0f;
        process_image_gen(smA, xa, k, out + base0, lane);
        process_image_gen(smA, xb, k, out + base1, lane);
    }
}

extern "C" void kernel_launch(void* const* d_in, const int* in_sizes, int n_in,
                              void* d_out, int out_size, void* d_ws, size_t ws_size,
                              hipStream_t stream) {
    const float* in   = (const float*)d_in[0];  // (16384,1,32,32)
    const float* w    = (const float*)d_in[1];  // (1,9)
    const float* wfac = (const float*)d_in[2];  // (1,1)
    float* out = (float*)d_out;                 // (1,16384,1,32,32)
    const int B = in_sizes[0] / 1024;           // 16384
    const int nblocks = B / 8;                  // 4 waves x 2 images each
    laplacian_fwd_kernel<<<nblocks, 256, 0, stream>>>(in, w, wfac, out);
}

// Round 10
// 113.580 us; speedup vs baseline: 1.0007x; 1.0007x over previous
//
#include <hip/hip_runtime.h>
#include <math.h>

// Grid 1024 x 256 (= exactly 4 blocks/CU, one residency generation).
// Each block = 4 independent waves; each wave owns 4 CONSECUTIVE images and
// runs a software-pipelined loop: issue loads of image i+1, then
// compute+store image i. Every compute phase has the next image's loads in
// flight and stores overlap next loads -> continuous HBM streaming instead
// of per-wave load/compute/store bursts (R9 post-mortem: 59%-of-peak BW
// matched the bursty-phase model).
//
// No __syncthreads: waves use disjoint LDS slices; LDS pipe is in-order
// within a wave; __builtin_amdgcn_wave_barrier() fences compiler motion.
//
// FAST PATH (all 8 neighbor weights equal — true for the Laplacian):
// conv = k0*sum9 + (k4-k0)*x, separable sum9: horizontal rowsums in
// registers (neighbors via zero-fill wave DPP shifts), staged to LDS,
// vertical = 2 b128 reads + own rowsum. Generic fallback: 9-fma conv.
// LDS slice: 34 rows x stride 36 + pad = 1228 floats; image col c at LDS
// col c+4 (16B-aligned b128). Rows 0/33 zeroed; cols 0,3 zeroed for the
// generic halo. Non-temporal output stores (best measured: R7/R8).

#define S 36
#define SLICE 1228

typedef float floatx4 __attribute__((ext_vector_type(4)));

template <int CTRL>
__device__ __forceinline__ float dppmov(float x) {
    // old = src => bound lanes keep x (identity for min/max)
    return __int_as_float(__builtin_amdgcn_update_dpp(
        __float_as_int(x), __float_as_int(x), CTRL, 0xf, 0xf, false));
}

template <int CTRL>
__device__ __forceinline__ float dppsh0(float x) {
    // zero-fill wave shift: old = 0, bound_ctrl = true
    return __int_as_float(__builtin_amdgcn_update_dpp(
        0, __float_as_int(x), CTRL, 0xf, 0xf, true));
}

__device__ __forceinline__ void wave64_minmax(float& mn, float& mx) {
    mn = fminf(mn, dppmov<0x111>(mn)); mx = fmaxf(mx, dppmov<0x111>(mx)); // row_shr:1
    mn = fminf(mn, dppmov<0x112>(mn)); mx = fmaxf(mx, dppmov<0x112>(mx)); // row_shr:2
    mn = fminf(mn, dppmov<0x114>(mn)); mx = fmaxf(mx, dppmov<0x114>(mx)); // row_shr:4
    mn = fminf(mn, dppmov<0x118>(mn)); mx = fmaxf(mx, dppmov<0x118>(mx)); // row_shr:8
    mn = fminf(mn, dppmov<0x142>(mn)); mx = fmaxf(mx, dppmov<0x142>(mx)); // row_bcast:15
    mn = fminf(mn, dppmov<0x143>(mn)); mx = fmaxf(mx, dppmov<0x143>(mx)); // row_bcast:31
    // lane 63 holds the wave-wide min / max
}

__device__ __forceinline__ float rd63(float v) {
    return __int_as_float(__builtin_amdgcn_readlane(__float_as_int(v), 63));
}

__device__ __forceinline__ void local_minmax16(const float v[4][4],
                                               float& mn, float& mx) {
    mn = v[0][0]; mx = v[0][0];
#pragma unroll
    for (int i = 0; i < 4; ++i)
#pragma unroll
        for (int j = 0; j < 4; ++j) {
            mn = fminf(mn, v[i][j]);
            mx = fmaxf(mx, v[i][j]);
        }
}

// Shared epilogue: reductions + normalize + clip + floor + nt store.
__device__ __forceinline__ void finish_image(
    const float4* __restrict__ x4, float conv[4][4],
    float* __restrict__ dst, int lane)
{
    float mn, mx;
    local_minmax16(conv, mn, mx);
    wave64_minmax(mn, mx);
    const float cmin = rd63(mn), cmax = rd63(mx);
    const float inv1 = 255.0f / fmaxf(cmax - cmin, 1e-6f);
    float sh[4][4];
#pragma unroll
    for (int i = 0; i < 4; ++i) {
        sh[i][0] = x4[i].x + (conv[i][0] - cmin) * inv1;
        sh[i][1] = x4[i].y + (conv[i][1] - cmin) * inv1;
        sh[i][2] = x4[i].z + (conv[i][2] - cmin) * inv1;
        sh[i][3] = x4[i].w + (conv[i][3] - cmin) * inv1;
    }
    local_minmax16(sh, mn, mx);
    wave64_minmax(mn, mx);
    const float smin = rd63(mn), smax = rd63(mx);
    const float inv2 = 255.0f / fminf(fmaxf(smax - smin, 1e-6f), 255.0f);
    const float c2 = -smin * inv2;
#pragma unroll
    for (int i = 0; i < 4; ++i) {
        floatx4 o;
        o.x = floorf(fminf(fmaxf(sh[i][0] * inv2 + c2, 0.0f), 255.0f));
        o.y = floorf(fminf(fmaxf(sh[i][1] * inv2 + c2, 0.0f), 255.0f));
        o.z = floorf(fminf(fmaxf(sh[i][2] * inv2 + c2, 0.0f), 255.0f));
        o.w = floorf(fminf(fmaxf(sh[i][3] * inv2 + c2, 0.0f), 255.0f));
        __builtin_nontemporal_store(o, (floatx4*)(dst + i * 256 + lane * 4));
    }
}

// Fast path: separable conv (all 8 neighbor coefficients = k0, center k4).
__device__ __forceinline__ void fast_image(
    float* __restrict__ sm, const float4* __restrict__ x4,
    float k0, float dk, float* __restrict__ dst, int lane)
{
    const int rbase = lane >> 3;        // 0..7
    const int col0  = (lane & 7) << 2;  // 0,4,...,28
    const bool ledge = (lane & 7) == 0;
    const bool redge = (lane & 7) == 7;

    float4 rs[4];
    __builtin_amdgcn_wave_barrier();
#pragma unroll
    for (int i = 0; i < 4; ++i) {
        const float4 m = x4[i];
        float lv = dppsh0<0x138>(m.w);  // wave_shr:1 -> lane-1's m.w
        float rv = dppsh0<0x130>(m.x);  // wave_shl:1 -> lane+1's m.x
        lv = ledge ? 0.0f : lv;
        rv = redge ? 0.0f : rv;
        const float t1 = m.x + m.y, t2 = m.z + m.w;
        rs[i].x = lv + t1; rs[i].y = t1 + m.z;
        rs[i].z = m.y + t2; rs[i].w = t2 + rv;
        *(float4*)&sm[(i * 8 + rbase + 1) * S + (col0 + 4)] = rs[i];
    }
    __builtin_amdgcn_wave_barrier();

    float conv[4][4];
#pragma unroll
    for (int i = 0; i < 4; ++i) {
        const int row = i * 8 + rbase;
        const float4 top = *(const float4*)&sm[ row      * S + col0 + 4];
        const float4 bot = *(const float4*)&sm[(row + 2) * S + col0 + 4];
        conv[i][0] = (top.x + rs[i].x + bot.x) * k0 + dk * x4[i].x;
        conv[i][1] = (top.y + rs[i].y + bot.y) * k0 + dk * x4[i].y;
        conv[i][2] = (top.z + rs[i].z + bot.z) * k0 + dk * x4[i].z;
        conv[i][3] = (top.w + rs[i].w + bot.w) * k0 + dk * x4[i].w;
    }
    __builtin_amdgcn_wave_barrier();

    finish_image(x4, conv, dst, lane);
}

// Generic fallback: raw 9-fma conv via LDS tile (halo cols 0,3 zeroed).
__device__ __forceinline__ void gen_image(
    float* __restrict__ sm, const float4* __restrict__ x4, const float* k,
    float* __restrict__ dst, int lane)
{
    const int rbase = lane >> 3;
    const int col0  = (lane & 7) << 2;

    __builtin_amdgcn_wave_barrier();
#pragma unroll
    for (int i = 0; i < 4; ++i)
        *(float4*)&sm[(i * 8 + rbase + 1) * S + (col0 + 4)] = x4[i];
    __builtin_amdgcn_wave_barrier();

    float conv[4][4];
#pragma unroll
    for (int i = 0; i < 4; ++i) {
        const int row = i * 8 + rbase;
        const float* pt = &sm[ row      * S + col0];
        const float* pm = &sm[(row + 1) * S + col0];
        const float* pb = &sm[(row + 2) * S + col0];
        const float  tl = pt[3], tr = pt[8];
        const float4 tm = *(const float4*)(pt + 4);
        const float  ml = pm[3], mr = pm[8];
        const float  bl = pb[3], br = pb[8];
        const float4 bm = *(const float4*)(pb + 4);
        const float4 m  = x4[i];
        conv[i][0] = k[0]*tl   + k[1]*tm.x + k[2]*tm.y
                   + k[3]*ml   + k[4]*m.x  + k[5]*m.y
                   + k[6]*bl   + k[7]*bm.x + k[8]*bm.y;
        conv[i][1] = k[0]*tm.x + k[1]*tm.y + k[2]*tm.z
                   + k[3]*m.x  + k[4]*m.y  + k[5]*m.z
                   + k[6]*bm.x + k[7]*bm.y + k[8]*bm.z;
        conv[i][2] = k[0]*tm.y + k[1]*tm.z + k[2]*tm.w
                   + k[3]*m.y  + k[4]*m.z  + k[5]*m.w
                   + k[6]*bm.y + k[7]*bm.z + k[8]*bm.w;
        conv[i][3] = k[0]*tm.z + k[1]*tm.w + k[2]*tr
                   + k[3]*m.z  + k[4]*m.w  + k[5]*mr
                   + k[6]*bm.z + k[7]*bm.w + k[8]*br;
    }
    __builtin_amdgcn_wave_barrier();

    finish_image(x4, conv, dst, lane);
}

__global__ __launch_bounds__(256) void laplacian_fwd_kernel(
    const float* __restrict__ in,      // (16384, 1, 32, 32)
    const float* __restrict__ weight,  // (1, 9)
    const float* __restrict__ wfac,    // (1, 1)
    float* __restrict__ out)           // (1, 16384, 1, 32, 32)
{
    __shared__ float lds[4 * SLICE];   // one slice per wave

    const int t    = threadIdx.x;
    const int w    = t >> 6;
    const int lane = t & 63;
    float* sm = &lds[w * SLICE];

    const int wave_id = blockIdx.x * 4 + w;      // 0..4095
    const size_t base = (size_t)wave_id * 4096;  // 4 consecutive images

    // Issue image-0 loads immediately.
    float4 x[4];
#pragma unroll
    for (int i = 0; i < 4; ++i)
        x[i] = *(const float4*)(in + base + i * 256 + lane * 4);

    // Border zeros once (serve all 4 images, both paths).
    if (lane < 36) { sm[lane] = 0.0f; sm[33 * S + lane] = 0.0f; }
    if (lane < 32) { sm[(lane + 1) * S] = 0.0f; sm[(lane + 1) * S + 3] = 0.0f; }
    if (lane == 0) sm[34 * S] = 0.0f;

    // Kernel coefficients (uniform).
    const float wf = fminf(fmaxf(wfac[0], 1.001f), 254.999f);
    float k[9];
#pragma unroll
    for (int i = 0; i < 9; ++i)
        k[i] = fminf(fmaxf(weight[i], -0.999f), 0.999f) * wf;

    const bool fast = (k[0] == k[1]) && (k[0] == k[2]) && (k[0] == k[3]) &&
                      (k[0] == k[5]) && (k[0] == k[6]) && (k[0] == k[7]) &&
                      (k[0] == k[8]);

    if (fast) {
        const float k0 = k[0];
        const float dk = k[4] - k[0];
#pragma unroll
        for (int im = 0; im < 4; ++im) {
            // Pipeline: issue next image's loads BEFORE this image's compute.
            float4 xn[4];
            if (im < 3) {
#pragma unroll
                for (int i = 0; i < 4; ++i)
                    xn[i] = *(const float4*)(in + base + (im + 1) * 1024 +
                                             i * 256 + lane * 4);
            }
            fast_image(sm, x, k0, dk, out + base + im * 1024, lane);
            if (im < 3) {
#pragma unroll
                for (int i = 0; i < 4; ++i) x[i] = xn[i];
            }
        }
    } else {
#pragma unroll
        for (int im = 0; im < 4; ++im) {
            float4 xn[4];
            if (im < 3) {
#pragma unroll
                for (int i = 0; i < 4; ++i)
                    xn[i] = *(const float4*)(in + base + (im + 1) * 1024 +
                                             i * 256 + lane * 4);
            }
            gen_image(sm, x, k, out + base + im * 1024, lane);
            if (im < 3) {
#pragma unroll
                for (int i = 0; i < 4; ++i) x[i] = xn[i];
            }
        }
    }
}

extern "C" void kernel_launch(void* const* d_in, const int* in_sizes, int n_in,
                              void* d_out, int out_size, void* d_ws, size_t ws_size,
                              hipStream_t stream) {
    const float* in   = (const float*)d_in[0];  // (16384,1,32,32)
    const float* w    = (const float*)d_in[1];  // (1,9)
    const float* wfac = (const float*)d_in[2];  // (1,1)
    float* out = (float*)d_out;                 // (1,16384,1,32,32)
    const int B = in_sizes[0] / 1024;           // 16384
    const int nblocks = B / 16;                 // 4 waves x 4 images each
    laplacian_fwd_kernel<<<nblocks, 256, 0, stream>>>(in, w, wfac, out);
}

// Round 11
// 110.032 us; speedup vs baseline: 1.0329x; 1.0322x over previous
//
#include <hip/hip_runtime.h>
#include <math.h>

// Grid 4096 x 256. Each block = 4 independent waves; each wave processes
// exactly ONE 32x32 image (16 px/thread). Rationale (R10 post-mortem):
// every config since R4 sat at ~16 waves/CU (LDS- or grid-capped); the
// residual 9us over the HBM floor tracks un-hidden per-wave serial phases
// (DPP reduction chains + divides with zero memory traffic). One image per
// wave minimizes live registers (~60-80 VGPR) and LDS (1 slice/wave,
// 19.6 KB/block -> 8 blocks/CU), targeting 24-32 waves/CU.
//
// No __syncthreads: waves use disjoint LDS slices; LDS pipe is in-order
// within a wave; __builtin_amdgcn_wave_barrier() fences compiler motion.
//
// FAST PATH (all 8 neighbor weights equal — true for the Laplacian):
// conv = k0*sum9 + (k4-k0)*x, separable: horizontal rowsums in registers
// (neighbors via zero-fill wave DPP shifts), staged to LDS, vertical =
// 2 b128 reads + own rowsum. Generic fallback: 9-fma conv via LDS tile.
// LDS slice: 34 rows x stride 36 + pad = 1228 floats; image col c at LDS
// col c+4 (16B-aligned b128). Rows 0/33 zeroed; cols 0,3 zeroed for the
// generic halo. Non-temporal stores (best measured: R7/R8).

#define S 36
#define SLICE 1228

typedef float floatx4 __attribute__((ext_vector_type(4)));

template <int CTRL>
__device__ __forceinline__ float dppmov(float x) {
    // old = src => bound lanes keep x (identity for min/max)
    return __int_as_float(__builtin_amdgcn_update_dpp(
        __float_as_int(x), __float_as_int(x), CTRL, 0xf, 0xf, false));
}

template <int CTRL>
__device__ __forceinline__ float dppsh0(float x) {
    // zero-fill wave shift: old = 0, bound_ctrl = true
    return __int_as_float(__builtin_amdgcn_update_dpp(
        0, __float_as_int(x), CTRL, 0xf, 0xf, true));
}

__device__ __forceinline__ void wave64_minmax(float& mn, float& mx) {
    mn = fminf(mn, dppmov<0x111>(mn)); mx = fmaxf(mx, dppmov<0x111>(mx)); // row_shr:1
    mn = fminf(mn, dppmov<0x112>(mn)); mx = fmaxf(mx, dppmov<0x112>(mx)); // row_shr:2
    mn = fminf(mn, dppmov<0x114>(mn)); mx = fmaxf(mx, dppmov<0x114>(mx)); // row_shr:4
    mn = fminf(mn, dppmov<0x118>(mn)); mx = fmaxf(mx, dppmov<0x118>(mx)); // row_shr:8
    mn = fminf(mn, dppmov<0x142>(mn)); mx = fmaxf(mx, dppmov<0x142>(mx)); // row_bcast:15
    mn = fminf(mn, dppmov<0x143>(mn)); mx = fmaxf(mx, dppmov<0x143>(mx)); // row_bcast:31
    // lane 63 holds the wave-wide min / max
}

__device__ __forceinline__ float rd63(float v) {
    return __int_as_float(__builtin_amdgcn_readlane(__float_as_int(v), 63));
}

__device__ __forceinline__ void local_minmax16(const float v[4][4],
                                               float& mn, float& mx) {
    mn = v[0][0]; mx = v[0][0];
#pragma unroll
    for (int i = 0; i < 4; ++i)
#pragma unroll
        for (int j = 0; j < 4; ++j) {
            mn = fminf(mn, v[i][j]);
            mx = fmaxf(mx, v[i][j]);
        }
}

// Shared epilogue: reductions + normalize + clip + floor + nt store.
// conv[][] is overwritten in place by sharpened values (register economy).
__device__ __forceinline__ void finish_image(
    const float4* __restrict__ x4, float conv[4][4],
    float* __restrict__ dst, int lane)
{
    float mn, mx;
    local_minmax16(conv, mn, mx);
    wave64_minmax(mn, mx);
    const float cmin = rd63(mn), cmax = rd63(mx);
    const float inv1 = 255.0f / fmaxf(cmax - cmin, 1e-6f);
#pragma unroll
    for (int i = 0; i < 4; ++i) {
        conv[i][0] = x4[i].x + (conv[i][0] - cmin) * inv1;
        conv[i][1] = x4[i].y + (conv[i][1] - cmin) * inv1;
        conv[i][2] = x4[i].z + (conv[i][2] - cmin) * inv1;
        conv[i][3] = x4[i].w + (conv[i][3] - cmin) * inv1;
    }
    local_minmax16(conv, mn, mx);
    wave64_minmax(mn, mx);
    const float smin = rd63(mn), smax = rd63(mx);
    const float inv2 = 255.0f / fminf(fmaxf(smax - smin, 1e-6f), 255.0f);
    const float c2 = -smin * inv2;
#pragma unroll
    for (int i = 0; i < 4; ++i) {
        floatx4 o;
        o.x = floorf(fminf(fmaxf(conv[i][0] * inv2 + c2, 0.0f), 255.0f));
        o.y = floorf(fminf(fmaxf(conv[i][1] * inv2 + c2, 0.0f), 255.0f));
        o.z = floorf(fminf(fmaxf(conv[i][2] * inv2 + c2, 0.0f), 255.0f));
        o.w = floorf(fminf(fmaxf(conv[i][3] * inv2 + c2, 0.0f), 255.0f));
        __builtin_nontemporal_store(o, (floatx4*)(dst + i * 256 + lane * 4));
    }
}

__global__ __launch_bounds__(256, 6) void laplacian_fwd_kernel(
    const float* __restrict__ in,      // (16384, 1, 32, 32)
    const float* __restrict__ weight,  // (1, 9)
    const float* __restrict__ wfac,    // (1, 1)
    float* __restrict__ out)           // (1, 16384, 1, 32, 32)
{
    __shared__ float lds[4 * SLICE];   // one slice per wave

    const int t    = threadIdx.x;
    const int w    = t >> 6;
    const int lane = t & 63;
    float* sm = &lds[w * SLICE];

    const int img = blockIdx.x * 4 + w;          // 0..16383
    const size_t base = (size_t)img * 1024;
    const float* src = in + base;
    float* dst = out + base;

    const int rbase = lane >> 3;        // 0..7
    const int col0  = (lane & 7) << 2;  // 0,4,...,28
    const bool ledge = (lane & 7) == 0;
    const bool redge = (lane & 7) == 7;

    // Issue the image's 4 b128 loads immediately.
    float4 x4[4];
#pragma unroll
    for (int i = 0; i < 4; ++i)
        x4[i] = *(const float4*)(src + i * 256 + lane * 4);

    // Border zeros: rows 0,33 full width; generic halo cols 0,3; pad.
    if (lane < 36) { sm[lane] = 0.0f; sm[33 * S + lane] = 0.0f; }
    if (lane < 32) { sm[(lane + 1) * S] = 0.0f; sm[(lane + 1) * S + 3] = 0.0f; }
    if (lane == 0) sm[34 * S] = 0.0f;

    // Kernel coefficients (uniform).
    const float wf = fminf(fmaxf(wfac[0], 1.001f), 254.999f);
    float k[9];
#pragma unroll
    for (int i = 0; i < 9; ++i)
        k[i] = fminf(fmaxf(weight[i], -0.999f), 0.999f) * wf;

    const bool fast = (k[0] == k[1]) && (k[0] == k[2]) && (k[0] == k[3]) &&
                      (k[0] == k[5]) && (k[0] == k[6]) && (k[0] == k[7]) &&
                      (k[0] == k[8]);

    float conv[4][4];

    if (fast) {
        const float k0 = k[0];
        const float dk = k[4] - k[0];

        // Horizontal rowsums in registers; stage to LDS (rs dies after conv).
        float4 rs[4];
        __builtin_amdgcn_wave_barrier();
#pragma unroll
        for (int i = 0; i < 4; ++i) {
            const float4 m = x4[i];
            float lv = dppsh0<0x138>(m.w);  // wave_shr:1 -> lane-1's m.w
            float rv = dppsh0<0x130>(m.x);  // wave_shl:1 -> lane+1's m.x
            lv = ledge ? 0.0f : lv;
            rv = redge ? 0.0f : rv;
            const float t1 = m.x + m.y, t2 = m.z + m.w;
            rs[i].x = lv + t1; rs[i].y = t1 + m.z;
            rs[i].z = m.y + t2; rs[i].w = t2 + rv;
            *(float4*)&sm[(i * 8 + rbase + 1) * S + (col0 + 4)] = rs[i];
        }
        __builtin_amdgcn_wave_barrier();

#pragma unroll
        for (int i = 0; i < 4; ++i) {
            const int row = i * 8 + rbase;
            const float4 top = *(const float4*)&sm[ row      * S + col0 + 4];
            const float4 bot = *(const float4*)&sm[(row + 2) * S + col0 + 4];
            conv[i][0] = (top.x + rs[i].x + bot.x) * k0 + dk * x4[i].x;
            conv[i][1] = (top.y + rs[i].y + bot.y) * k0 + dk * x4[i].y;
            conv[i][2] = (top.z + rs[i].z + bot.z) * k0 + dk * x4[i].z;
            conv[i][3] = (top.w + rs[i].w + bot.w) * k0 + dk * x4[i].w;
        }
        __builtin_amdgcn_wave_barrier();
    } else {
        // Generic: raw pixels to LDS, 9-fma conv (halo cols 0,3 zeroed).
        __builtin_amdgcn_wave_barrier();
#pragma unroll
        for (int i = 0; i < 4; ++i)
            *(float4*)&sm[(i * 8 + rbase + 1) * S + (col0 + 4)] = x4[i];
        __builtin_amdgcn_wave_barrier();

#pragma unroll
        for (int i = 0; i < 4; ++i) {
            const int row = i * 8 + rbase;
            const float* pt = &sm[ row      * S + col0];
            const float* pm = &sm[(row + 1) * S + col0];
            const float* pb = &sm[(row + 2) * S + col0];
            const float  tl = pt[3], tr = pt[8];
            const float4 tm = *(const float4*)(pt + 4);
            const float  ml = pm[3], mr = pm[8];
            const float  bl = pb[3], br = pb[8];
            const float4 bm = *(const float4*)(pb + 4);
            const float4 m  = x4[i];
            conv[i][0] = k[0]*tl   + k[1]*tm.x + k[2]*tm.y
                       + k[3]*ml   + k[4]*m.x  + k[5]*m.y
                       + k[6]*bl   + k[7]*bm.x + k[8]*bm.y;
            conv[i][1] = k[0]*tm.x + k[1]*tm.y + k[2]*tm.z
                       + k[3]*m.x  + k[4]*m.y  + k[5]*m.z
                       + k[6]*bm.x + k[7]*bm.y + k[8]*bm.z;
            conv[i][2] = k[0]*tm.y + k[1]*tm.z + k[2]*tm.w
                       + k[3]*m.y  + k[4]*m.z  + k[5]*m.w
                       + k[6]*bm.y + k[7]*bm.z + k[8]*bm.w;
            conv[i][3] = k[0]*tm.z + k[1]*tm.w + k[2]*tr
                       + k[3]*m.z  + k[4]*m.w  + k[5]*mr
                       + k[6]*bm.z + k[7]*bm.w + k[8]*br;
        }
        __builtin_amdgcn_wave_barrier();
    }

    finish_image(x4, conv, dst, lane);
}

extern "C" void kernel_launch(void* const* d_in, const int* in_sizes, int n_in,
                              void* d_out, int out_size, void* d_ws, size_t ws_size,
                              hipStream_t stream) {
    const float* in   = (const float*)d_in[0];  // (16384,1,32,32)
    const float* w    = (const float*)d_in[1];  // (1,9)
    const float* wfac = (const float*)d_in[2];  // (1,1)
    float* out = (float*)d_out;                 // (1,16384,1,32,32)
    const int B = in_sizes[0] / 1024;           // 16384
    const int nblocks = B / 4;                  // 4 waves x 1 image each
    laplacian_fwd_kernel<<<nblocks, 256, 0, stream>>>(in, w, wfac, out);
}